// Round 8
// baseline (357.744 us; speedup 1.0000x reference)
//
#include <hip/hip_runtime.h>

// SepConv: out[b,c,i,j] = sum_{u,v} img[b,c,i+u,j+v] * vert[b,u,i,j] * hori[b,v,i,j]
// B=8, C=3, W=H=512, K=13, Wo=Ho=500.
//
// R14: R13's reg-staging (validated: BW 2.07 -> 2.97 TB/s) minus its spill.
// R13 post-mortem: allocator kept VGPR=52 and spilled ~8/10 staging float4s
// to scratch (WRITE 227MB vs 24MB output; +106MB scratch re-reads) -- each
// quad took global->scratch->LDS. Session allocator rules:
//   (1) accumulators survive full-size; (2) read-only resident arrays get
//   sunk (R10); (3) >~8 simultaneously-live staging temps get spilled
//   rather than growing the ~52-reg budget (R13).
// Fix: stage in TWO 5-deep batches (vert fully: 5 loads -> 5 ds_writes;
// then hori fully), sched_barrier(0) between so the scheduler can't merge
// them back into one 10-live cluster. Peak live staging = 5 float4 = 20
// VGPRs -- fits the 52-reg budget (tmp not yet live). Queue depth during a
// batch = 5 x 1KB = 5KB/wave; 18 resident waves -> up to ~90KB/CU posted
// vs ~9KB Little's-law need. Everything else is R6 verbatim (block(128,3),
// grid(500,8), 52KB LDS, tmp[4][13] compute, depth-1 img rotation).

#define KK 13
#define NB 8
#define NC 3
#define IW 512
#define IH 512
#define WO 500
#define HO 500
#define QROW 125              // float4 quads per 500-col row
#define NT 384                // 128 j-lanes x 3 channels
#define NQ (KK * QROW)        // 1625 float4s per weight array
#define NSTEP 5               // ceil(1625/384)

__global__ __launch_bounds__(NT) void sepconv_kernel(
    const float* __restrict__ img,
    const float* __restrict__ hori,
    const float* __restrict__ vert,
    float* __restrict__ out)
{
    __shared__ float4 s_vert[NQ];   // [u][quad], 26000 B
    __shared__ float4 s_hori[NQ];   // [v][quad], 26000 B

    const int tid = threadIdx.y * 128 + threadIdx.x;
    const int i = blockIdx.x;       // output row
    const int b = blockIdx.y;       // batch

    const size_t khw = (size_t)WO * HO;      // 250000
    const size_t rs4 = khw / 4;              // 62500 float4 between k-slices
    const float4* vsrc = (const float4*)(vert + (size_t)b * KK * khw + (size_t)i * HO);
    const float4* hsrc = (const float4*)(hori + (size_t)b * KK * khw + (size_t)i * HO);

    // ---- stage batch 1: vert. 5 independent dwordx4 loads (5KB/wave in
    // flight), then 5 ds_write_b128. Peak live staging regs = 20.
    {
        float4 sv[NSTEP];
        #pragma unroll
        for (int s = 0; s < NSTEP; ++s) {
            const int f = s * NT + tid;
            if (f < NQ) {
                const unsigned u = (unsigned)f / QROW;
                const unsigned q = (unsigned)f - u * QROW;
                sv[s] = vsrc[(size_t)u * rs4 + q];
            }
        }
        #pragma unroll
        for (int s = 0; s < NSTEP; ++s) {
            const int f = s * NT + tid;
            if (f < NQ) s_vert[f] = sv[s];
        }
    }
    // fence: keep batch 2's loads from being hoisted into batch 1's live
    // range (would recreate R13's 10-live cluster -> spill).
    __builtin_amdgcn_sched_barrier(0);

    // ---- stage batch 2: hori, same shape ----
    {
        float4 sh[NSTEP];
        #pragma unroll
        for (int s = 0; s < NSTEP; ++s) {
            const int f = s * NT + tid;
            if (f < NQ) {
                const unsigned u = (unsigned)f / QROW;
                const unsigned q = (unsigned)f - u * QROW;
                sh[s] = hsrc[(size_t)u * rs4 + q];
            }
        }
        #pragma unroll
        for (int s = 0; s < NSTEP; ++s) {
            const int f = s * NT + tid;
            if (f < NQ) s_hori[f] = sh[s];
        }
    }
    __syncthreads();

    const int tj = threadIdx.x;     // j-quad
    const int c  = threadIdx.y;     // channel
    if (tj >= QROW) return;
    const int j0 = tj * 4;

    const float* ibase = img + (((size_t)(b * NC + c) * IW) + i) * IH + j0;

    float tmp[4][KK];
    #pragma unroll
    for (int jq = 0; jq < 4; ++jq)
        #pragma unroll
        for (int v = 0; v < KK; ++v)
            tmp[jq][v] = 0.0f;

    // ---- pipeline prologue: img row u = 0 ----
    float4 c0 = *(const float4*)(ibase + 0);
    float4 c1 = *(const float4*)(ibase + 4);
    float4 c2 = *(const float4*)(ibase + 8);
    float4 c3 = *(const float4*)(ibase + 12);

    #pragma unroll
    for (int u = 0; u < KK; ++u) {
        // issue next img row before this iteration's FMAs
        float4 n0, n1, n2, n3;
        if (u < KK - 1) {
            const float* rp = ibase + (size_t)(u + 1) * IH;
            n0 = *(const float4*)(rp + 0);
            n1 = *(const float4*)(rp + 4);
            n2 = *(const float4*)(rp + 8);
            n3 = *(const float4*)(rp + 12);
        }

        const float4 vt = s_vert[u * QROW + tj];   // ds_read_b128

        float row[16];
        row[0]  = c0.x; row[1]  = c0.y; row[2]  = c0.z; row[3]  = c0.w;
        row[4]  = c1.x; row[5]  = c1.y; row[6]  = c1.z; row[7]  = c1.w;
        row[8]  = c2.x; row[9]  = c2.y; row[10] = c2.z; row[11] = c2.w;
        row[12] = c3.x; row[13] = c3.y; row[14] = c3.z; row[15] = c3.w;

        #pragma unroll
        for (int v = 0; v < KK; ++v) {
            tmp[0][v] += row[0 + v] * vt.x;
            tmp[1][v] += row[1 + v] * vt.y;
            tmp[2][v] += row[2 + v] * vt.z;
            tmp[3][v] += row[3 + v] * vt.w;
        }

        if (u < KK - 1) {
            c0 = n0; c1 = n1; c2 = n2; c3 = n3;
        }
    }

    // ---- epilogue: fold hori from LDS ----
    float4 o = make_float4(0.f, 0.f, 0.f, 0.f);
    #pragma unroll
    for (int v = 0; v < KK; ++v) {
        const float4 hv = s_hori[v * QROW + tj];
        o.x += tmp[0][v] * hv.x;
        o.y += tmp[1][v] * hv.y;
        o.z += tmp[2][v] * hv.z;
        o.w += tmp[3][v] * hv.w;
    }

    float* op = out + (((size_t)(b * NC + c) * WO) + i) * HO + j0;
    *(float4*)op = o;
}

extern "C" void kernel_launch(void* const* d_in, const int* in_sizes, int n_in,
                              void* d_out, int out_size, void* d_ws, size_t ws_size,
                              hipStream_t stream) {
    const float* img  = (const float*)d_in[0];
    const float* hori = (const float*)d_in[1];
    const float* vert = (const float*)d_in[2];
    float* out = (float*)d_out;

    dim3 block(128, 3, 1);        // x = j-quads (125 used), y = channel
    dim3 grid(WO, NB, 1);         // x = output row i, y = batch
    hipLaunchKernelGGL(sepconv_kernel, grid, block, 0, stream, img, hori, vert, out);
}